// Round 6
// baseline (121.785 us; speedup 1.0000x reference)
//
#include <hip/hip_runtime.h>
#include <hip/hip_bf16.h>
#include <stdint.h>

// Problem constants
#define B_ 16
#define T_ 2048
#define D_ 256
#define QK_ 64
#define LOG2E 1.44269504088896340736f

typedef _Float16 f16;
typedef _Float16 f16x2 __attribute__((ext_vector_type(2)));
typedef __fp16 fp16x2 __attribute__((ext_vector_type(2)));
typedef _Float16 f16x8 __attribute__((ext_vector_type(8)));
typedef float f32x16 __attribute__((ext_vector_type(16)));

// raw v_exp_f32 / v_log_f32 (base-2); avoids libm guard sequences
__device__ __forceinline__ float fexp2(float x) {
#if __has_builtin(__builtin_amdgcn_exp2f)
    return __builtin_amdgcn_exp2f(x);
#else
    return exp2f(x);
#endif
}
__device__ __forceinline__ float flog2(float x) {
#if __has_builtin(__builtin_amdgcn_logf)
    return __builtin_amdgcn_logf(x);
#else
    return log2f(x);
#endif
}
// packed f32x2 -> f16x2 (v_cvt_pkrtz_f16_f32); RTZ rounding
__device__ __forceinline__ f16x2 cvt2(float a, float b) {
#if __has_builtin(__builtin_amdgcn_cvt_pkrtz)
    fp16x2 r = __builtin_amdgcn_cvt_pkrtz(a, b);
    return __builtin_bit_cast(f16x2, r);
#else
    f16x2 r; r[0] = (f16)a; r[1] = (f16)b; return r;
#endif
}

// ---------------------------------------------------------------------------
// Kernel 0: cast Wq||Wk -> f16 wh[128][256] (rne)
// ---------------------------------------------------------------------------
__global__ __launch_bounds__(256) void wconv_kernel(
    const float* __restrict__ Wq, const float* __restrict__ Wk,
    f16* __restrict__ wh)
{
    const int i = blockIdx.x * 256 + threadIdx.x;   // 0..32767
    const float v = (i < 64 * 256) ? Wq[i] : Wk[i - 64 * 256];
    wh[i] = (f16)v;
}

// ---------------------------------------------------------------------------
// Kernel 1: MFMA projection, LDS-free mainloop.
//   [qh|k2h][b][t][e]; k2h scaled by 0.125*(1+clip(sl)^2)*log2e.
// Block: 256 thr / 4 waves, 32 t-rows; wave wv owns output cols wv*32..+31.
// A-frags: direct global 32B loads of x + cvt_pkrtz (L1 reuse across waves).
// B-frags: direct 16B loads from wh (L2-resident).
// MFMA 32x32x16_f16 layout (verified R2):
//   A: row=l&31, k=(l>>5)*8+j ; B: col=l&31, k=(l>>5)*8+j
//   C: col=l&31, row=(i&3)+8*(i>>2)+4*(l>>5)
// ---------------------------------------------------------------------------
__global__ __launch_bounds__(256) void proj_mfma(
    const float* __restrict__ x, const float* __restrict__ sl,
    const f16* __restrict__ wh,
    const float* __restrict__ bq, const float* __restrict__ bk,
    f16* __restrict__ qh, f16* __restrict__ k2h)
{
    __shared__ __align__(16) f16 hout[32 * 128];   // 8 KB transpose buffer
    __shared__ float ksc[32];
    const int b = blockIdx.y, t0 = blockIdx.x * 32;
    const int tid = threadIdx.x;
    const int wv = tid >> 6, l = tid & 63, lo = l & 31, hi = l >> 5;

    if (tid < 32) {
        float s = sl[(size_t)b * T_ + t0 + tid];
        s = fminf(fmaxf(s, 0.f), 1.f);
        ksc[tid] = 0.125f * (1.f + s * s) * LOG2E;
    }

    const int c0 = wv * 32;
    const float* xrow = x + (size_t)(b * T_ + t0 + lo) * D_ + hi * 8;
    const f16*  wrow  = wh + (size_t)(c0 + lo) * D_ + hi * 8;

    f32x16 acc;
    #pragma unroll
    for (int i = 0; i < 16; ++i) acc[i] = 0.f;

    #pragma unroll
    for (int ks = 0; ks < 16; ++ks) {
        const float4 a0 = *(const float4*)(xrow + ks * 16);
        const float4 a1 = *(const float4*)(xrow + ks * 16 + 4);
        union { f16x2 h2[4]; f16x8 h8; } u;
        u.h2[0] = cvt2(a0.x, a0.y); u.h2[1] = cvt2(a0.z, a0.w);
        u.h2[2] = cvt2(a1.x, a1.y); u.h2[3] = cvt2(a1.z, a1.w);
        const f16x8 bf = *(const f16x8*)(wrow + ks * 16);
        acc = __builtin_amdgcn_mfma_f32_32x32x16_f16(u.h8, bf, acc, 0, 0, 0);
    }

    const int e = c0 + lo;
    const float bias = (e < 64) ? bq[e] : bk[e - 64];
    __syncthreads();                       // ksc ready
    #pragma unroll
    for (int i = 0; i < 16; ++i) {
        const int row = (i & 3) + 8 * (i >> 2) + 4 * hi;
        float v = acc[i] + bias;
        if (e >= 64) v *= ksc[row];
        hout[row * 128 + e] = (f16)v;      // rne store
    }
    __syncthreads();
    // coalesced stores: 32 rows x 16 chunks(16B), 2 per thread
    #pragma unroll
    for (int i = 0; i < 2; ++i) {
        const int f = i * 256 + tid;
        const int rr = f >> 4, j = f & 15;
        const f16x8 v = *(const f16x8*)(hout + rr * 128 + j * 8);
        if (j < 8) *(f16x8*)(qh  + (size_t)(b * T_ + t0 + rr) * QK_ + j * 8) = v;
        else       *(f16x8*)(k2h + (size_t)(b * T_ + t0 + rr) * QK_ + (j - 8) * 8) = v;
    }
}

// ---------------------------------------------------------------------------
// Kernel 2 (Z partial): zpart[(b*4+ck)][t] = sum_{s in 512-chunk ck}
//     2^(S2[t,s] + maskbias[s])
// Barrier-free, LDS-free: B-frags direct from k2h (L1/L2). grid (64,B),
// 256 thr / 4 waves; wave wv owns t-rows t0+wv*32..+31 (A in registers).
// ---------------------------------------------------------------------------
__global__ __launch_bounds__(256) void z_part(
    const f16* __restrict__ qh, const f16* __restrict__ k2h,
    const int* __restrict__ mask, float* __restrict__ zpart)
{
    const int b = blockIdx.y;
    const int t0 = (blockIdx.x & 15) * 128;
    const int ck = blockIdx.x >> 4;
    const int sbase = ck * 512;
    const int tid = threadIdx.x;
    const int wv = tid >> 6, l = tid & 63, lo = l & 31, hi = l >> 5;

    const f16* qrow = qh + (size_t)(b * T_ + t0 + wv * 32 + lo) * QK_ + hi * 8;
    f16x8 a[4];
    #pragma unroll
    for (int kc = 0; kc < 4; ++kc) a[kc] = *(const f16x8*)(qrow + kc * 16);

    float zp[16];
    #pragma unroll
    for (int i = 0; i < 16; ++i) zp[i] = 0.f;

    const f16* kbase = k2h + (size_t)(b * T_) * QK_ + hi * 8;
    const int* mbase = mask + b * T_;

    for (int g = 0; g < 16; ++g) {
        const int scol = sbase + g * 32 + lo;
        const float mb = mbase[scol] ? 0.f : -1e9f;
        f32x16 c;
        #pragma unroll
        for (int i = 0; i < 16; ++i) c[i] = mb;
        const f16* kr = kbase + (size_t)scol * QK_;
        #pragma unroll
        for (int kc = 0; kc < 4; ++kc) {
            const f16x8 bf = *(const f16x8*)(kr + kc * 16);
            c = __builtin_amdgcn_mfma_f32_32x32x16_f16(a[kc], bf, c, 0, 0, 0);
        }
        #pragma unroll
        for (int i = 0; i < 16; ++i) zp[i] += fexp2(c[i]);
    }

    // reduce across the 32 column-lanes (s) per hi-half
    #pragma unroll
    for (int off = 1; off <= 16; off <<= 1)
        #pragma unroll
        for (int i = 0; i < 16; ++i) zp[i] += __shfl_xor(zp[i], off);

    if (lo == 0) {
        #pragma unroll
        for (int i = 0; i < 16; ++i) {
            const int row = (i & 3) + 8 * (i >> 2) + 4 * hi;
            zpart[(size_t)(b * 4 + ck) * T_ + t0 + wv * 32 + row] = zp[i];
        }
    }
}

// ---------------------------------------------------------------------------
// Kernel 3 (W partial): wpart[(b*4+tc)][s] = sum_{t in 512-chunk tc}
//     2^(S2[t,s] + lz[t]),  lz[t] = -log2(sum_ck zpart[ck][t])
// Mirror of z_part; lz computed inline (one per lane per group).
// ---------------------------------------------------------------------------
__global__ __launch_bounds__(256) void w_part(
    const f16* __restrict__ qh, const f16* __restrict__ k2h,
    const float* __restrict__ zpart, float* __restrict__ wpart)
{
    const int b = blockIdx.y;
    const int s0b = (blockIdx.x & 15) * 128;
    const int tc = blockIdx.x >> 4;
    const int tbase = tc * 512;
    const int tid = threadIdx.x;
    const int wv = tid >> 6, l = tid & 63, lo = l & 31, hi = l >> 5;

    const f16* krow = k2h + (size_t)(b * T_ + s0b + wv * 32 + lo) * QK_ + hi * 8;
    f16x8 a[4];
    #pragma unroll
    for (int kc = 0; kc < 4; ++kc) a[kc] = *(const f16x8*)(krow + kc * 16);

    float wp[16];
    #pragma unroll
    for (int i = 0; i < 16; ++i) wp[i] = 0.f;

    const f16* qbase = qh + (size_t)(b * T_) * QK_ + hi * 8;
    const float* zb = zpart + (size_t)(b * 4) * T_;

    for (int g = 0; g < 16; ++g) {
        const int tcol = tbase + g * 32 + lo;
        const float z = zb[tcol] + zb[T_ + tcol] + zb[2 * T_ + tcol] + zb[3 * T_ + tcol];
        const float lz = -flog2(z);
        f32x16 c;
        #pragma unroll
        for (int i = 0; i < 16; ++i) c[i] = lz;
        const f16* qr = qbase + (size_t)tcol * QK_;
        #pragma unroll
        for (int kc = 0; kc < 4; ++kc) {
            const f16x8 bf = *(const f16x8*)(qr + kc * 16);
            c = __builtin_amdgcn_mfma_f32_32x32x16_f16(a[kc], bf, c, 0, 0, 0);
        }
        #pragma unroll
        for (int i = 0; i < 16; ++i) wp[i] += fexp2(c[i]);
    }

    #pragma unroll
    for (int off = 1; off <= 16; off <<= 1)
        #pragma unroll
        for (int i = 0; i < 16; ++i) wp[i] += __shfl_xor(wp[i], off);

    if (lo == 0) {
        #pragma unroll
        for (int i = 0; i < 16; ++i) {
            const int row = (i & 3) + 8 * (i >> 2) + 4 * hi;
            wpart[(size_t)(b * 4 + tc) * T_ + s0b + wv * 32 + row] = wp[i];
        }
    }
}

// ---------------------------------------------------------------------------
// Kernel 4: per 32-row chunk: w[s] = mask[s]/T * sum_c wpart[c][s];
//   ypart[b][ch][d] = sum_s w[s]*x[b,s,d];  swp[b][ch] = sum_s w[s]
// ---------------------------------------------------------------------------
__global__ __launch_bounds__(256) void y_fused(
    const float* __restrict__ x, const float* __restrict__ wpart,
    const int* __restrict__ mask, float* __restrict__ ypart,
    float* __restrict__ swp)
{
    __shared__ float wloc[32];
    const int b  = blockIdx.y;
    const int ch = blockIdx.x;
    const int tid = threadIdx.x;

    if (tid < 32) {
        const int s = ch * 32 + tid;
        float v = wpart[(size_t)(b * 4 + 0) * T_ + s]
                + wpart[(size_t)(b * 4 + 1) * T_ + s]
                + wpart[(size_t)(b * 4 + 2) * T_ + s]
                + wpart[(size_t)(b * 4 + 3) * T_ + s];
        v *= mask[b * T_ + s] ? (1.f / (float)T_) : 0.f;
        wloc[tid] = v;
        float sv = v;
        #pragma unroll
        for (int off = 1; off <= 16; off <<= 1) sv += __shfl_xor(sv, off);
        if (tid == 0) swp[b * 64 + ch] = sv;
    }
    __syncthreads();

    const int d = tid;
    const float* xb = x + ((size_t)b * T_ + ch * 32) * D_;
    float acc = 0.f;
    #pragma unroll 8
    for (int s = 0; s < 32; ++s) acc += wloc[s] * xb[(size_t)s * D_ + d];
    ypart[((size_t)b * 64 + ch) * D_ + d] = acc;
}

// ---------------------------------------------------------------------------
// Kernel 5: out[b][e] = sum_d y[b,d]*Wv[e,d] + bv[e]*sum_s w[b,s]
// ---------------------------------------------------------------------------
__global__ __launch_bounds__(256) void outkernel(
    const float* __restrict__ ypart, const float* __restrict__ swp,
    const float* __restrict__ Wv, const float* __restrict__ bv,
    float* __restrict__ out)
{
    __shared__ __align__(16) float ys[D_];
    __shared__ float sw0;
    const int b   = blockIdx.x;
    const int tid = threadIdx.x;

    float yv = 0.f;
    #pragma unroll
    for (int ch = 0; ch < 64; ++ch) yv += ypart[((size_t)b * 64 + ch) * D_ + tid];
    ys[tid] = yv;

    float s = (tid < 64) ? swp[b * 64 + tid] : 0.f;
    #pragma unroll
    for (int off = 1; off <= 32; off <<= 1) s += __shfl_xor(s, off);
    if (tid == 0) sw0 = s;
    __syncthreads();

    const float sw = sw0;
    const float4* wv4 = (const float4*)(Wv + (size_t)tid * D_);
    const float4* ys4 = (const float4*)ys;
    float o = 0.f;
    for (int i = 0; i < D_ / 4; ++i) {
        const float4 a = wv4[i];
        const float4 y = ys4[i];
        o += a.x * y.x + a.y * y.y + a.z * y.z + a.w * y.w;
    }
    out[(size_t)b * D_ + tid] = o + bv[tid] * sw;
}

// ---------------------------------------------------------------------------
extern "C" void kernel_launch(void* const* d_in, const int* in_sizes, int n_in,
                              void* d_out, int out_size, void* d_ws, size_t ws_size,
                              hipStream_t stream)
{
    const float* x    = (const float*)d_in[0];
    const float* sl   = (const float*)d_in[1];
    const int*   mask = (const int*)d_in[2];
    const float* Wq   = (const float*)d_in[3];
    const float* bq   = (const float*)d_in[4];
    const float* Wk   = (const float*)d_in[5];
    const float* bk   = (const float*)d_in[6];
    const float* Wv   = (const float*)d_in[7];
    const float* bv   = (const float*)d_in[8];
    float* out = (float*)d_out;

    // workspace: qh 4MB | k2h 4MB | wh 64KB | zpart 512KB | wpart 512KB
    //            | swp 4KB | yp 1MB
    f16*   qh    = (f16*)d_ws;
    f16*   k2h   = qh + (size_t)B_ * T_ * QK_;
    f16*   wh    = k2h + (size_t)B_ * T_ * QK_;
    float* zpart = (float*)(wh + 128 * D_);
    float* wpart = zpart + (size_t)B_ * 4 * T_;
    float* swp   = wpart + (size_t)B_ * 4 * T_;
    float* yp    = swp + B_ * 64;

    wconv_kernel<<<dim3(128), 256, 0, stream>>>(Wq, Wk, wh);
    proj_mfma  <<<dim3(T_ / 32, B_), 256, 0, stream>>>(x, sl, wh, bq, bk, qh, k2h);
    z_part     <<<dim3(64, B_), 256, 0, stream>>>(qh, k2h, mask, zpart);
    w_part     <<<dim3(64, B_), 256, 0, stream>>>(qh, k2h, zpart, wpart);
    y_fused    <<<dim3(64, B_), 256, 0, stream>>>(x, wpart, mask, yp, swp);
    outkernel  <<<dim3(B_), 256, 0, stream>>>(yp, swp, Wv, bv, out);
}

// Round 7
// 90.365 us; speedup vs baseline: 1.3477x; 1.3477x over previous
//
#include <hip/hip_runtime.h>
#include <hip/hip_bf16.h>
#include <stdint.h>

// Problem constants
#define B_ 16
#define T_ 2048
#define D_ 256
#define QK_ 64
#define LOG2E 1.44269504088896340736f

typedef _Float16 f16;
typedef _Float16 f16x2 __attribute__((ext_vector_type(2)));
typedef __fp16 fp16x2 __attribute__((ext_vector_type(2)));
typedef _Float16 f16x8 __attribute__((ext_vector_type(8)));
typedef float f32x16 __attribute__((ext_vector_type(16)));

// async global->LDS, 16B per lane. LDS dest = wave-uniform base + lane*16 (HW).
__device__ __forceinline__ void gload_lds16(const void* g, void* l) {
    __builtin_amdgcn_global_load_lds(
        (const __attribute__((address_space(1))) uint32_t*)g,
        (__attribute__((address_space(3))) uint32_t*)l, 16, 0, 0);
}

// raw v_exp_f32 / v_log_f32 (base-2)
__device__ __forceinline__ float fexp2(float x) {
#if __has_builtin(__builtin_amdgcn_exp2f)
    return __builtin_amdgcn_exp2f(x);
#else
    return exp2f(x);
#endif
}
__device__ __forceinline__ float flog2(float x) {
#if __has_builtin(__builtin_amdgcn_logf)
    return __builtin_amdgcn_logf(x);
#else
    return log2f(x);
#endif
}
// packed f32x2 -> f16x2 (v_cvt_pkrtz_f16_f32)
__device__ __forceinline__ f16x2 cvt2(float a, float b) {
#if __has_builtin(__builtin_amdgcn_cvt_pkrtz)
    fp16x2 r = __builtin_amdgcn_cvt_pkrtz(a, b);
    return __builtin_bit_cast(f16x2, r);
#else
    f16x2 r; r[0] = (f16)a; r[1] = (f16)b; return r;
#endif
}
__device__ __forceinline__ f16x8 cvt8(const float* p) {
    union { f16x2 h2[4]; f16x8 h8; } u;
    const float4 a0 = *(const float4*)p;
    const float4 a1 = *(const float4*)(p + 4);
    u.h2[0] = cvt2(a0.x, a0.y); u.h2[1] = cvt2(a0.z, a0.w);
    u.h2[2] = cvt2(a1.x, a1.y); u.h2[3] = cvt2(a1.z, a1.w);
    return u.h8;
}

// ---------------------------------------------------------------------------
// Kernel 1: MFMA projection. [qh|k2h][b][t][e]; k2h scaled by
//   0.125*(1+clip(sl)^2)*log2e. Block: 256 thr / 4 waves, 32 t-rows.
// x staged in LDS (f32->f16, 32-slot XOR swizzle, coalesced loads);
// W converted in-loop from f32 Wq/Wk (L2-resident, line-contiguous reads).
// MFMA 32x32x16_f16 layout (verified R2):
//   A: row=l&31, k=(l>>5)*8+j ; B: col=l&31, k=(l>>5)*8+j
//   C: col=l&31, row=(i&3)+8*(i>>2)+4*(l>>5)
// ---------------------------------------------------------------------------
__global__ __launch_bounds__(256) void proj_mfma(
    const float* __restrict__ x, const float* __restrict__ sl,
    const float* __restrict__ Wq, const float* __restrict__ Wk,
    const float* __restrict__ bq, const float* __restrict__ bk,
    f16* __restrict__ qh, f16* __restrict__ k2h)
{
    __shared__ __align__(16) f16 xs[32 * D_];   // 16 KB; reused as hout[32][128]
    __shared__ float ksc[32];
    const int b = blockIdx.y, t0 = blockIdx.x * 32;
    const int tid = threadIdx.x;
    const int wv = tid >> 6, l = tid & 63, lo = l & 31, hi = l >> 5;

    // stage x tile [32 rows][256] -> f16 swizzled; coalesced 32B/thread x 4
    #pragma unroll
    for (int i = 0; i < 4; ++i) {
        const int f = i * 256 + tid;
        const int r = f >> 5, j = f & 31;
        const f16x8 h = cvt8(x + (size_t)(b * T_ + t0 + r) * D_ + j * 8);
        *(f16x8*)(xs + r * D_ + ((j ^ r) << 3)) = h;
    }
    if (tid < 32) {
        float s = sl[(size_t)b * T_ + t0 + tid];
        s = fminf(fmaxf(s, 0.f), 1.f);
        ksc[tid] = 0.125f * (1.f + s * s) * LOG2E;
    }
    __syncthreads();

    const int c0 = wv * 32;
    const int e = c0 + lo;
    const float* wrow = ((e < 64) ? (Wq + (size_t)e * D_)
                                  : (Wk + (size_t)(e - 64) * D_)) + hi * 8;

    f32x16 acc;
    #pragma unroll
    for (int i = 0; i < 16; ++i) acc[i] = 0.f;

    #pragma unroll
    for (int ks = 0; ks < 16; ++ks) {
        const f16x8 a  = *(const f16x8*)(xs + lo * D_ + ((((ks << 1) + hi) ^ lo) << 3));
        const f16x8 bf = cvt8(wrow + ks * 16);
        acc = __builtin_amdgcn_mfma_f32_32x32x16_f16(a, bf, acc, 0, 0, 0);
    }

    const float bias = (e < 64) ? bq[e] : bk[e - 64];
    __syncthreads();                     // xs reads done -> reuse as hout
    f16* hout = xs;
    #pragma unroll
    for (int i = 0; i < 16; ++i) {
        const int row = (i & 3) + 8 * (i >> 2) + 4 * hi;
        float v = acc[i] + bias;
        if (e >= 64) v *= ksc[row];
        hout[row * 128 + e] = (f16)v;    // rne store
    }
    __syncthreads();
    // coalesced stores: 32 rows x 16 chunks(16B), 2 per thread
    #pragma unroll
    for (int i = 0; i < 2; ++i) {
        const int f = i * 256 + tid;
        const int rr = f >> 4, j = f & 15;
        const f16x8 v = *(const f16x8*)(hout + rr * 128 + j * 8);
        if (j < 8) *(f16x8*)(qh  + (size_t)(b * T_ + t0 + rr) * QK_ + j * 8) = v;
        else       *(f16x8*)(k2h + (size_t)(b * T_ + t0 + rr) * QK_ + (j - 8) * 8) = v;
    }
}

// ---------------------------------------------------------------------------
// Kernel 2 (Z partial): zpart[(b*16+ck)][t] = sum_{s in 128-chunk ck}
//     2^(S2[t,s] + maskbias[s])
// One 16KB k2-tile per block, single barrier, no loop. grid (256,B) ->
// 8 blocks/CU, ~100% occupancy. A-frags direct from qh (4 instrs/wave).
// ---------------------------------------------------------------------------
__global__ __launch_bounds__(256) void z_part(
    const f16* __restrict__ qh, const f16* __restrict__ k2h,
    const int* __restrict__ mask, float* __restrict__ zpart)
{
    __shared__ __align__(16) f16 kt[128 * QK_];   // 16 KB
    const int b = blockIdx.y;
    const int t0 = (blockIdx.x & 15) * 128;
    const int ck = blockIdx.x >> 4;
    const int sbase = ck * 128;
    const int tid = threadIdx.x;
    const int wv = tid >> 6, l = tid & 63, lo = l & 31, hi = l >> 5;

    // stage k2 tile [128 s][64 e], pre-swizzled source, linear LDS dest
    {
        const char* src = (const char*)(k2h + (size_t)(b * T_ + sbase) * QK_);
        #pragma unroll
        for (int i = 0; i < 4; ++i) {
            const int o = wv * 4096 + i * 1024 + l * 16;
            const int r = o >> 7, jc = (o >> 4) & 7;
            gload_lds16(src + r * 128 + ((jc ^ (r & 7)) << 4),
                        (char*)kt + wv * 4096 + i * 1024);
        }
    }

    const f16* qrow = qh + (size_t)(b * T_ + t0 + wv * 32 + lo) * QK_ + hi * 8;
    f16x8 a[4];
    #pragma unroll
    for (int kc = 0; kc < 4; ++kc) a[kc] = *(const f16x8*)(qrow + kc * 16);

    float zp[16];
    #pragma unroll
    for (int i = 0; i < 16; ++i) zp[i] = 0.f;

    __syncthreads();   // staging complete (vmcnt drained by barrier)

    #pragma unroll
    for (int cg = 0; cg < 4; ++cg) {
        const int srow = cg * 32 + lo;
        const float mb = mask[b * T_ + sbase + srow] ? 0.f : -1e9f;
        f32x16 c;
        #pragma unroll
        for (int i = 0; i < 16; ++i) c[i] = mb;
        #pragma unroll
        for (int kc = 0; kc < 4; ++kc) {
            const int jcc = (kc * 2 + hi) ^ (srow & 7);
            const f16x8 bf = *(const f16x8*)((const char*)kt + srow * 128 + (jcc << 4));
            c = __builtin_amdgcn_mfma_f32_32x32x16_f16(a[kc], bf, c, 0, 0, 0);
        }
        #pragma unroll
        for (int i = 0; i < 16; ++i) zp[i] += fexp2(c[i]);
    }

    // reduce across the 32 column-lanes (s)
    #pragma unroll
    for (int off = 1; off <= 16; off <<= 1)
        #pragma unroll
        for (int i = 0; i < 16; ++i) zp[i] += __shfl_xor(zp[i], off);

    if (lo == 0) {
        #pragma unroll
        for (int i = 0; i < 16; ++i) {
            const int row = (i & 3) + 8 * (i >> 2) + 4 * hi;
            zpart[(size_t)(b * 16 + ck) * T_ + t0 + wv * 32 + row] = zp[i];
        }
    }
}

// ---------------------------------------------------------------------------
// Kernel 3 (W partial): wpart[(b*16+tc)][s] = sum_{t in 128-chunk tc}
//     2^(S2[t,s] + lz[t]),  lz[t] = -log2(sum_ck zpart[ck][t])
// Mirror of z_part; lz precomputed per block into LDS.
// ---------------------------------------------------------------------------
__global__ __launch_bounds__(256) void w_part(
    const f16* __restrict__ qh, const f16* __restrict__ k2h,
    const float* __restrict__ zpart, float* __restrict__ wpart)
{
    __shared__ __align__(16) f16 qt[128 * QK_];   // 16 KB
    __shared__ float lz_s[128];
    const int b = blockIdx.y;
    const int s0b = (blockIdx.x & 15) * 128;
    const int tc = blockIdx.x >> 4;
    const int tbase = tc * 128;
    const int tid = threadIdx.x;
    const int wv = tid >> 6, l = tid & 63, lo = l & 31, hi = l >> 5;

    {
        const char* src = (const char*)(qh + (size_t)(b * T_ + tbase) * QK_);
        #pragma unroll
        for (int i = 0; i < 4; ++i) {
            const int o = wv * 4096 + i * 1024 + l * 16;
            const int r = o >> 7, jc = (o >> 4) & 7;
            gload_lds16(src + r * 128 + ((jc ^ (r & 7)) << 4),
                        (char*)qt + wv * 4096 + i * 1024);
        }
    }
    if (tid < 128) {   // lz for this block's 128 t-cols (coalesced)
        const float* zb = zpart + (size_t)(b * 16) * T_ + tbase + tid;
        float z = 0.f;
        #pragma unroll
        for (int ckk = 0; ckk < 16; ++ckk) z += zb[(size_t)ckk * T_];
        lz_s[tid] = -flog2(z);
    }

    const f16* krow = k2h + (size_t)(b * T_ + s0b + wv * 32 + lo) * QK_ + hi * 8;
    f16x8 a[4];
    #pragma unroll
    for (int kc = 0; kc < 4; ++kc) a[kc] = *(const f16x8*)(krow + kc * 16);

    float wp[16];
    #pragma unroll
    for (int i = 0; i < 16; ++i) wp[i] = 0.f;

    __syncthreads();

    #pragma unroll
    for (int cg = 0; cg < 4; ++cg) {
        const int trow = cg * 32 + lo;
        const float bias = lz_s[trow];
        f32x16 c;
        #pragma unroll
        for (int i = 0; i < 16; ++i) c[i] = bias;
        #pragma unroll
        for (int kc = 0; kc < 4; ++kc) {
            const int jcc = (kc * 2 + hi) ^ (trow & 7);
            const f16x8 bf = *(const f16x8*)((const char*)qt + trow * 128 + (jcc << 4));
            c = __builtin_amdgcn_mfma_f32_32x32x16_f16(a[kc], bf, c, 0, 0, 0);
        }
        #pragma unroll
        for (int i = 0; i < 16; ++i) wp[i] += fexp2(c[i]);
    }

    #pragma unroll
    for (int off = 1; off <= 16; off <<= 1)
        #pragma unroll
        for (int i = 0; i < 16; ++i) wp[i] += __shfl_xor(wp[i], off);

    if (lo == 0) {
        #pragma unroll
        for (int i = 0; i < 16; ++i) {
            const int row = (i & 3) + 8 * (i >> 2) + 4 * hi;
            wpart[(size_t)(b * 16 + tc) * T_ + s0b + wv * 32 + row] = wp[i];
        }
    }
}

// ---------------------------------------------------------------------------
// Kernel 4: per 32-row chunk: w[s] = mask[s]/T * sum_c wpart[c][s];
//   ypart[b][ch][d] = sum_s w[s]*x[b,s,d];  swp[b][ch] = sum_s w[s]
// ---------------------------------------------------------------------------
__global__ __launch_bounds__(256) void y_fused(
    const float* __restrict__ x, const float* __restrict__ wpart,
    const int* __restrict__ mask, float* __restrict__ ypart,
    float* __restrict__ swp)
{
    __shared__ float wloc[32];
    const int b  = blockIdx.y;
    const int ch = blockIdx.x;
    const int tid = threadIdx.x;

    if (tid < 32) {
        const int s = ch * 32 + tid;
        const float* wb = wpart + (size_t)(b * 16) * T_ + s;
        float v = 0.f;
        #pragma unroll
        for (int ckk = 0; ckk < 16; ++ckk) v += wb[(size_t)ckk * T_];
        v *= mask[b * T_ + s] ? (1.f / (float)T_) : 0.f;
        wloc[tid] = v;
        float sv = v;
        #pragma unroll
        for (int off = 1; off <= 16; off <<= 1) sv += __shfl_xor(sv, off);
        if (tid == 0) swp[b * 64 + ch] = sv;
    }
    __syncthreads();

    const int d = tid;
    const float* xb = x + ((size_t)b * T_ + ch * 32) * D_;
    float acc = 0.f;
    #pragma unroll 8
    for (int s = 0; s < 32; ++s) acc += wloc[s] * xb[(size_t)s * D_ + d];
    ypart[((size_t)b * 64 + ch) * D_ + d] = acc;
}

// ---------------------------------------------------------------------------
// Kernel 5: out[b][e] = sum_d y[b,d]*Wv[e,d] + bv[e]*sum_s w[b,s]
// ---------------------------------------------------------------------------
__global__ __launch_bounds__(256) void outkernel(
    const float* __restrict__ ypart, const float* __restrict__ swp,
    const float* __restrict__ Wv, const float* __restrict__ bv,
    float* __restrict__ out)
{
    __shared__ __align__(16) float ys[D_];
    __shared__ float sw0;
    const int b   = blockIdx.x;
    const int tid = threadIdx.x;

    float yv = 0.f;
    #pragma unroll
    for (int ch = 0; ch < 64; ++ch) yv += ypart[((size_t)b * 64 + ch) * D_ + tid];
    ys[tid] = yv;

    float s = (tid < 64) ? swp[b * 64 + tid] : 0.f;
    #pragma unroll
    for (int off = 1; off <= 32; off <<= 1) s += __shfl_xor(s, off);
    if (tid == 0) sw0 = s;
    __syncthreads();

    const float sw = sw0;
    const float4* wv4 = (const float4*)(Wv + (size_t)tid * D_);
    const float4* ys4 = (const float4*)ys;
    float o = 0.f;
    for (int i = 0; i < D_ / 4; ++i) {
        const float4 a = wv4[i];
        const float4 y = ys4[i];
        o += a.x * y.x + a.y * y.y + a.z * y.z + a.w * y.w;
    }
    out[(size_t)b * D_ + tid] = o + bv[tid] * sw;
}

// ---------------------------------------------------------------------------
extern "C" void kernel_launch(void* const* d_in, const int* in_sizes, int n_in,
                              void* d_out, int out_size, void* d_ws, size_t ws_size,
                              hipStream_t stream)
{
    const float* x    = (const float*)d_in[0];
    const float* sl   = (const float*)d_in[1];
    const int*   mask = (const int*)d_in[2];
    const float* Wq   = (const float*)d_in[3];
    const float* bq   = (const float*)d_in[4];
    const float* Wk   = (const float*)d_in[5];
    const float* bk   = (const float*)d_in[6];
    const float* Wv   = (const float*)d_in[7];
    const float* bv   = (const float*)d_in[8];
    float* out = (float*)d_out;

    // workspace: qh 4MB | k2h 4MB | zpart 2MB | wpart 2MB | swp 4KB | yp 1MB
    f16*   qh    = (f16*)d_ws;
    f16*   k2h   = qh + (size_t)B_ * T_ * QK_;
    float* zpart = (float*)(k2h + (size_t)B_ * T_ * QK_);
    float* wpart = zpart + (size_t)B_ * 16 * T_;
    float* swp   = wpart + (size_t)B_ * 16 * T_;
    float* yp    = swp + B_ * 64;

    proj_mfma<<<dim3(T_ / 32, B_), 256, 0, stream>>>(x, sl, Wq, Wk, bq, bk, qh, k2h);
    z_part   <<<dim3(256, B_), 256, 0, stream>>>(qh, k2h, mask, zpart);
    w_part   <<<dim3(256, B_), 256, 0, stream>>>(qh, k2h, zpart, wpart);
    y_fused  <<<dim3(64, B_), 256, 0, stream>>>(x, wpart, mask, yp, swp);
    outkernel<<<dim3(B_), 256, 0, stream>>>(yp, swp, Wv, bv, out);
}

// Round 8
// 82.602 us; speedup vs baseline: 1.4744x; 1.0940x over previous
//
#include <hip/hip_runtime.h>
#include <hip/hip_bf16.h>
#include <stdint.h>

// Problem constants
#define B_ 16
#define T_ 2048
#define D_ 256
#define QK_ 64
#define LOG2E 1.44269504088896340736f

typedef _Float16 f16;
typedef _Float16 f16x2 __attribute__((ext_vector_type(2)));
typedef __fp16 fp16x2 __attribute__((ext_vector_type(2)));
typedef _Float16 f16x8 __attribute__((ext_vector_type(8)));
typedef float f32x16 __attribute__((ext_vector_type(16)));

// async global->LDS, 16B per lane. LDS dest = wave-uniform base + lane*16 (HW).
__device__ __forceinline__ void gload_lds16(const void* g, void* l) {
    __builtin_amdgcn_global_load_lds(
        (const __attribute__((address_space(1))) uint32_t*)g,
        (__attribute__((address_space(3))) uint32_t*)l, 16, 0, 0);
}

// raw v_exp_f32 / v_log_f32 (base-2)
__device__ __forceinline__ float fexp2(float x) {
#if __has_builtin(__builtin_amdgcn_exp2f)
    return __builtin_amdgcn_exp2f(x);
#else
    return exp2f(x);
#endif
}
__device__ __forceinline__ float flog2(float x) {
#if __has_builtin(__builtin_amdgcn_logf)
    return __builtin_amdgcn_logf(x);
#else
    return log2f(x);
#endif
}
// packed f32x2 -> f16x2 (v_cvt_pkrtz_f16_f32)
__device__ __forceinline__ f16x2 cvt2(float a, float b) {
#if __has_builtin(__builtin_amdgcn_cvt_pkrtz)
    fp16x2 r = __builtin_amdgcn_cvt_pkrtz(a, b);
    return __builtin_bit_cast(f16x2, r);
#else
    f16x2 r; r[0] = (f16)a; r[1] = (f16)b; return r;
#endif
}
__device__ __forceinline__ f16x8 cvt8(const float* p) {
    union { f16x2 h2[4]; f16x8 h8; } u;
    const float4 a0 = *(const float4*)p;
    const float4 a1 = *(const float4*)(p + 4);
    u.h2[0] = cvt2(a0.x, a0.y); u.h2[1] = cvt2(a0.z, a0.w);
    u.h2[2] = cvt2(a1.x, a1.y); u.h2[3] = cvt2(a1.z, a1.w);
    return u.h8;
}

// ---------------------------------------------------------------------------
// Kernel 1: MFMA projection. Emits FOUR layouts:
//   qh/k2h row-major [b][t][e]      (consumed by z/w LDS staging, coalesced)
//   qf/kf  frag-major [b][t/32 tile][kc(4)][hi(2)][lo(32)][8]
//          = value at row t0+lo, k = kc*16+hi*8+j  (consumed as MFMA A-frags,
//          one wave A-load = 4 x contiguous 1KB)
// k2 scaled by 0.125*(1+clip(sl)^2)*log2e.  Block: 4 waves, 32 t-rows.
// MFMA 32x32x16_f16 layout (verified R2):
//   A: row=l&31, k=(l>>5)*8+j ; B: col=l&31, k=(l>>5)*8+j
//   C: col=l&31, row=(i&3)+8*(i>>2)+4*(l>>5)
// ---------------------------------------------------------------------------
__global__ __launch_bounds__(256) void proj_mfma(
    const float* __restrict__ x, const float* __restrict__ sl,
    const float* __restrict__ Wq, const float* __restrict__ Wk,
    const float* __restrict__ bq, const float* __restrict__ bk,
    f16* __restrict__ qh, f16* __restrict__ k2h,
    f16* __restrict__ qf, f16* __restrict__ kf)
{
    __shared__ __align__(16) f16 xs[32 * D_];   // 16 KB; reused as hout[32][128]
    __shared__ float ksc[32];
    const int b = blockIdx.y, tile = blockIdx.x, t0 = tile * 32;
    const int tid = threadIdx.x;
    const int wv = tid >> 6, l = tid & 63, lo = l & 31, hi = l >> 5;

    // stage x tile [32 rows][256] -> f16 swizzled; coalesced 32B/thread x 4
    #pragma unroll
    for (int i = 0; i < 4; ++i) {
        const int f = i * 256 + tid;
        const int r = f >> 5, j = f & 31;
        const f16x8 h = cvt8(x + (size_t)(b * T_ + t0 + r) * D_ + j * 8);
        *(f16x8*)(xs + r * D_ + ((j ^ r) << 3)) = h;
    }
    if (tid < 32) {
        float s = sl[(size_t)b * T_ + t0 + tid];
        s = fminf(fmaxf(s, 0.f), 1.f);
        ksc[tid] = 0.125f * (1.f + s * s) * LOG2E;
    }
    __syncthreads();

    const int c0 = wv * 32;
    const int e = c0 + lo;
    const float* wrow = ((e < 64) ? (Wq + (size_t)e * D_)
                                  : (Wk + (size_t)(e - 64) * D_)) + hi * 8;

    f32x16 acc;
    #pragma unroll
    for (int i = 0; i < 16; ++i) acc[i] = 0.f;

    #pragma unroll
    for (int ks = 0; ks < 16; ++ks) {
        const f16x8 a  = *(const f16x8*)(xs + lo * D_ + ((((ks << 1) + hi) ^ lo) << 3));
        const f16x8 bf = cvt8(wrow + ks * 16);
        acc = __builtin_amdgcn_mfma_f32_32x32x16_f16(a, bf, acc, 0, 0, 0);
    }

    const float bias = (e < 64) ? bq[e] : bk[e - 64];
    __syncthreads();                     // xs reads done -> reuse as hout
    f16* hout = xs;
    #pragma unroll
    for (int i = 0; i < 16; ++i) {
        const int row = (i & 3) + 8 * (i >> 2) + 4 * hi;
        float v = acc[i] + bias;
        if (e >= 64) v *= ksc[row];
        hout[row * 128 + e] = (f16)v;    // rne store
    }
    __syncthreads();
    // row-major stores: 32 rows x 16 chunks(16B), 2 per thread
    #pragma unroll
    for (int i = 0; i < 2; ++i) {
        const int f = i * 256 + tid;
        const int rr = f >> 4, j = f & 15;
        const f16x8 v = *(const f16x8*)(hout + rr * 128 + j * 8);
        if (j < 8) *(f16x8*)(qh  + (size_t)(b * T_ + t0 + rr) * QK_ + j * 8) = v;
        else       *(f16x8*)(k2h + (size_t)(b * T_ + t0 + rr) * QK_ + (j - 8) * 8) = v;
    }
    // frag-major stores: chunk tid = [kc][hi][lo]; 1 q + 1 k2 chunk per thread
    {
        const int kc2 = tid >> 6, hi2 = (tid >> 5) & 1, lo2 = tid & 31;
        const f16* srcq = hout + lo2 * 128 + kc2 * 16 + hi2 * 8;
        const size_t tb = ((size_t)b * 64 + tile) * 2048 + tid * 8;
        *(f16x8*)(qf + tb) = *(const f16x8*)srcq;
        *(f16x8*)(kf + tb) = *(const f16x8*)(srcq + 64);
    }
}

// ---------------------------------------------------------------------------
// Kernel 2 (Z partial): zpart[(b*16+ck)][t] = sum_{s in 128-chunk ck}
//     2^(S2[t,s] + maskbias[s])
// One 16KB k2-tile per block; A-frags coalesced from qf; LDS-transpose
// reduction (reuses staging LDS). grid (256,B) -> ~8 blocks/CU.
// ---------------------------------------------------------------------------
__global__ __launch_bounds__(256) void z_part(
    const f16* __restrict__ qf, const f16* __restrict__ k2h,
    const int* __restrict__ mask, float* __restrict__ zpart)
{
    __shared__ __align__(16) f16 kt[128 * QK_];   // 16 KB
    const int b = blockIdx.y;
    const int tIdx = blockIdx.x & 15, t0 = tIdx * 128;
    const int ck = blockIdx.x >> 4,  sbase = ck * 128;
    const int tid = threadIdx.x;
    const int wv = tid >> 6, l = tid & 63, lo = l & 31, hi = l >> 5;

    // stage k2 tile [128 s][64 e], pre-swizzled source, linear LDS dest
    {
        const char* src = (const char*)(k2h + (size_t)(b * T_ + sbase) * QK_);
        #pragma unroll
        for (int i = 0; i < 4; ++i) {
            const int o = wv * 4096 + i * 1024 + l * 16;
            const int r = o >> 7, jc = (o >> 4) & 7;
            gload_lds16(src + r * 128 + ((jc ^ (r & 7)) << 4),
                        (char*)kt + wv * 4096 + i * 1024);
        }
    }

    // A-frags: coalesced from qf (wave reads 4 x 1KB contiguous)
    const f16* abase = qf + ((size_t)b * 64 + tIdx * 4 + wv) * 2048 + l * 8;
    f16x8 a[4];
    #pragma unroll
    for (int kc = 0; kc < 4; ++kc) a[kc] = *(const f16x8*)(abase + kc * 512);

    float zp[16];
    #pragma unroll
    for (int i = 0; i < 16; ++i) zp[i] = 0.f;

    __syncthreads();   // staging complete

    #pragma unroll
    for (int cg = 0; cg < 4; ++cg) {
        const int srow = cg * 32 + lo;
        const float mb = mask[b * T_ + sbase + srow] ? 0.f : -1e9f;
        f32x16 c;
        #pragma unroll
        for (int i = 0; i < 16; ++i) c[i] = mb;
        #pragma unroll
        for (int kc = 0; kc < 4; ++kc) {
            const int jcc = (kc * 2 + hi) ^ (srow & 7);
            const f16x8 bf = *(const f16x8*)((const char*)kt + srow * 128 + (jcc << 4));
            c = __builtin_amdgcn_mfma_f32_32x32x16_f16(a[kc], bf, c, 0, 0, 0);
        }
        #pragma unroll
        for (int i = 0; i < 16; ++i) zp[i] += fexp2(c[i]);
    }

    // LDS-transpose reduction over the 32 s-lanes
    __syncthreads();                 // kt reads done -> reuse as red[128][32]
    float* red = (float*)kt;
    #pragma unroll
    for (int i = 0; i < 16; ++i) {
        const int row = wv * 32 + (i & 3) + 8 * (i >> 2) + 4 * hi;
        const int col = (lo & 3) | ((((lo >> 2) ^ row) & 7) << 2);
        red[row * 32 + col] = zp[i];
    }
    __syncthreads();
    if (tid < 128) {
        float s = 0.f;
        #pragma unroll
        for (int c = 0; c < 8; ++c) {
            const float4 v = *(const float4*)(red + tid * 32 + (((c ^ tid) & 7) << 2));
            s += v.x + v.y + v.z + v.w;
        }
        zpart[(size_t)(b * 16 + ck) * T_ + t0 + tid] = s;
    }
}

// ---------------------------------------------------------------------------
// Kernel 3 (W partial): wpart[(b*16+tc)][s] = sum_{t in 128-chunk tc}
//     2^(S2[t,s] + lz[t]),  lz[t] = -log2(sum_ck zpart[ck][t])
// Mirror of z_part: A-frags from kf, stages q rows, lz in LDS.
// ---------------------------------------------------------------------------
__global__ __launch_bounds__(256) void w_part(
    const f16* __restrict__ kf, const f16* __restrict__ qh,
    const float* __restrict__ zpart, float* __restrict__ wpart)
{
    __shared__ __align__(16) f16 qt[128 * QK_];   // 16 KB
    __shared__ float lz_s[128];
    const int b = blockIdx.y;
    const int sIdx = blockIdx.x & 15, s0b = sIdx * 128;
    const int tc = blockIdx.x >> 4,  tbase = tc * 128;
    const int tid = threadIdx.x;
    const int wv = tid >> 6, l = tid & 63, lo = l & 31, hi = l >> 5;

    {
        const char* src = (const char*)(qh + (size_t)(b * T_ + tbase) * QK_);
        #pragma unroll
        for (int i = 0; i < 4; ++i) {
            const int o = wv * 4096 + i * 1024 + l * 16;
            const int r = o >> 7, jc = (o >> 4) & 7;
            gload_lds16(src + r * 128 + ((jc ^ (r & 7)) << 4),
                        (char*)qt + wv * 4096 + i * 1024);
        }
    }
    if (tid < 128) {   // lz for this block's 128 t-cols (coalesced)
        const float* zb = zpart + (size_t)(b * 16) * T_ + tbase + tid;
        float z = 0.f;
        #pragma unroll
        for (int ckk = 0; ckk < 16; ++ckk) z += zb[(size_t)ckk * T_];
        lz_s[tid] = -flog2(z);
    }

    const f16* abase = kf + ((size_t)b * 64 + sIdx * 4 + wv) * 2048 + l * 8;
    f16x8 a[4];
    #pragma unroll
    for (int kc = 0; kc < 4; ++kc) a[kc] = *(const f16x8*)(abase + kc * 512);

    float wp[16];
    #pragma unroll
    for (int i = 0; i < 16; ++i) wp[i] = 0.f;

    __syncthreads();

    #pragma unroll
    for (int cg = 0; cg < 4; ++cg) {
        const int trow = cg * 32 + lo;
        const float bias = lz_s[trow];
        f32x16 c;
        #pragma unroll
        for (int i = 0; i < 16; ++i) c[i] = bias;
        #pragma unroll
        for (int kc = 0; kc < 4; ++kc) {
            const int jcc = (kc * 2 + hi) ^ (trow & 7);
            const f16x8 bf = *(const f16x8*)((const char*)qt + trow * 128 + (jcc << 4));
            c = __builtin_amdgcn_mfma_f32_32x32x16_f16(a[kc], bf, c, 0, 0, 0);
        }
        #pragma unroll
        for (int i = 0; i < 16; ++i) wp[i] += fexp2(c[i]);
    }

    __syncthreads();                 // qt reads done -> reuse as red[128][32]
    float* red = (float*)qt;
    #pragma unroll
    for (int i = 0; i < 16; ++i) {
        const int row = wv * 32 + (i & 3) + 8 * (i >> 2) + 4 * hi;
        const int col = (lo & 3) | ((((lo >> 2) ^ row) & 7) << 2);
        red[row * 32 + col] = wp[i];
    }
    __syncthreads();
    if (tid < 128) {
        float s = 0.f;
        #pragma unroll
        for (int c = 0; c < 8; ++c) {
            const float4 v = *(const float4*)(red + tid * 32 + (((c ^ tid) & 7) << 2));
            s += v.x + v.y + v.z + v.w;
        }
        wpart[(size_t)(b * 16 + tc) * T_ + s0b + tid] = s;
    }
}

// ---------------------------------------------------------------------------
// Kernel 4: per 32-row chunk: w[s] = mask[s]/T * sum_c wpart[c][s];
//   ypart[b][ch][d] = sum_s w[s]*x[b,s,d];  swp[b][ch] = sum_s w[s]
// ---------------------------------------------------------------------------
__global__ __launch_bounds__(256) void y_fused(
    const float* __restrict__ x, const float* __restrict__ wpart,
    const int* __restrict__ mask, float* __restrict__ ypart,
    float* __restrict__ swp)
{
    __shared__ float wloc[32];
    const int b  = blockIdx.y;
    const int ch = blockIdx.x;
    const int tid = threadIdx.x;

    if (tid < 32) {
        const int s = ch * 32 + tid;
        const float* wb = wpart + (size_t)(b * 16) * T_ + s;
        float v = 0.f;
        #pragma unroll
        for (int ckk = 0; ckk < 16; ++ckk) v += wb[(size_t)ckk * T_];
        v *= mask[b * T_ + s] ? (1.f / (float)T_) : 0.f;
        wloc[tid] = v;
        float sv = v;
        #pragma unroll
        for (int off = 1; off <= 16; off <<= 1) sv += __shfl_xor(sv, off);
        if (tid == 0) swp[b * 64 + ch] = sv;
    }
    __syncthreads();

    const int d = tid;
    const float* xb = x + ((size_t)b * T_ + ch * 32) * D_;
    float acc = 0.f;
    #pragma unroll 8
    for (int s = 0; s < 32; ++s) acc += wloc[s] * xb[(size_t)s * D_ + d];
    ypart[((size_t)b * 64 + ch) * D_ + d] = acc;
}

// ---------------------------------------------------------------------------
// Kernel 5: out[b][e] = sum_d y[b,d]*Wv[e,d] + bv[e]*sum_s w[b,s]
// ---------------------------------------------------------------------------
__global__ __launch_bounds__(256) void outkernel(
    const float* __restrict__ ypart, const float* __restrict__ swp,
    const float* __restrict__ Wv, const float* __restrict__ bv,
    float* __restrict__ out)
{
    __shared__ __align__(16) float ys[D_];
    __shared__ float sw0;
    const int b   = blockIdx.x;
    const int tid = threadIdx.x;

    float yv = 0.f;
    #pragma unroll
    for (int ch = 0; ch < 64; ++ch) yv += ypart[((size_t)b * 64 + ch) * D_ + tid];
    ys[tid] = yv;

    float s = (tid < 64) ? swp[b * 64 + tid] : 0.f;
    #pragma unroll
    for (int off = 1; off <= 32; off <<= 1) s += __shfl_xor(s, off);
    if (tid == 0) sw0 = s;
    __syncthreads();

    const float sw = sw0;
    const float4* wv4 = (const float4*)(Wv + (size_t)tid * D_);
    const float4* ys4 = (const float4*)ys;
    float o = 0.f;
    for (int i = 0; i < D_ / 4; ++i) {
        const float4 a = wv4[i];
        const float4 y = ys4[i];
        o += a.x * y.x + a.y * y.y + a.z * y.z + a.w * y.w;
    }
    out[(size_t)b * D_ + tid] = o + bv[tid] * sw;
}

// ---------------------------------------------------------------------------
extern "C" void kernel_launch(void* const* d_in, const int* in_sizes, int n_in,
                              void* d_out, int out_size, void* d_ws, size_t ws_size,
                              hipStream_t stream)
{
    const float* x    = (const float*)d_in[0];
    const float* sl   = (const float*)d_in[1];
    const int*   mask = (const int*)d_in[2];
    const float* Wq   = (const float*)d_in[3];
    const float* bq   = (const float*)d_in[4];
    const float* Wk   = (const float*)d_in[5];
    const float* bk   = (const float*)d_in[6];
    const float* Wv   = (const float*)d_in[7];
    const float* bv   = (const float*)d_in[8];
    float* out = (float*)d_out;

    // workspace: qh 4 | k2h 4 | qf 4 | kf 4 | zpart 2 | wpart 2 | swp | yp (MB)
    f16*   qh    = (f16*)d_ws;
    f16*   k2h   = qh  + (size_t)B_ * T_ * QK_;
    f16*   qf    = k2h + (size_t)B_ * T_ * QK_;
    f16*   kf    = qf  + (size_t)B_ * T_ * QK_;
    float* zpart = (float*)(kf + (size_t)B_ * T_ * QK_);
    float* wpart = zpart + (size_t)B_ * 16 * T_;
    float* swp   = wpart + (size_t)B_ * 16 * T_;
    float* yp    = swp + B_ * 64;

    proj_mfma<<<dim3(T_ / 32, B_), 256, 0, stream>>>(x, sl, Wq, Wk, bq, bk, qh, k2h, qf, kf);
    z_part   <<<dim3(256, B_), 256, 0, stream>>>(qf, k2h, mask, zpart);
    w_part   <<<dim3(256, B_), 256, 0, stream>>>(kf, qh, zpart, wpart);
    y_fused  <<<dim3(64, B_), 256, 0, stream>>>(x, wpart, mask, yp, swp);
    outkernel<<<dim3(B_), 256, 0, stream>>>(yp, swp, Wv, bv, out);
}